// Round 1
// baseline (1321.154 us; speedup 1.0000x reference)
//
#include <hip/hip_runtime.h>

typedef __attribute__((ext_vector_type(8))) short bf16x8;
typedef __attribute__((ext_vector_type(4))) float f32x4;

__device__ __forceinline__ unsigned short f2bf(float f){
  unsigned u = __builtin_bit_cast(unsigned, f);
  u += 0x7FFFu + ((u >> 16) & 1u);
  return (unsigned short)(u >> 16);
}
__device__ __forceinline__ float bf2f(unsigned short b){
  unsigned u = ((unsigned)b) << 16;
  return __builtin_bit_cast(float, u);
}
__device__ __forceinline__ float sigmoidf_(float x){ return 1.f/(1.f + __expf(-x)); }
__device__ __forceinline__ float tanhf_(float x){
  float a = fabsf(x);
  float t = __expf(-2.f*a);
  float r = (1.f - t)/(1.f + t);
  return copysignf(r, x);
}

struct WF { bf16x8 hi, lo; };

// D += (Ah+Al)*(Bh+Bl), dropping Al*Bl  (~fp32 precision, fp32 accumulate)
__device__ __forceinline__ f32x4 mm3(bf16x8 ah, bf16x8 al, const WF& B, f32x4 D){
  D = __builtin_amdgcn_mfma_f32_16x16x32_bf16(al, B.hi, D, 0, 0, 0);
  D = __builtin_amdgcn_mfma_f32_16x16x32_bf16(ah, B.lo, D, 0, 0, 0);
  D = __builtin_amdgcn_mfma_f32_16x16x32_bf16(ah, B.hi, D, 0, 0, 0);
  return D;
}

// B-fragment loader: lane holds B[k = quad*8+j][n = lane&15] = W[row][k]
__device__ __forceinline__ WF load_wf(const float* W, int ldk, int row, int k0, int kmax){
  WF f;
  #pragma unroll
  for (int j = 0; j < 8; j++){
    int k = k0 + j;
    float v = (k < kmax) ? W[row*ldk + k] : 0.f;
    unsigned short hb = f2bf(v);
    f.hi[j] = (short)hb;
    f.lo[j] = (short)f2bf(v - bf2f(hb));
  }
  return f;
}

// ---------------- GRU: 2 layers fused, 16 nodes per workgroup ----------------
__global__ __launch_bounds__(256, 1)
void gru_kernel(const float* __restrict__ x,
                const float* __restrict__ Wih0, const float* __restrict__ Whh0,
                const float* __restrict__ bih0, const float* __restrict__ bhh0,
                const float* __restrict__ Wih1, const float* __restrict__ Whh1,
                const float* __restrict__ bih1, const float* __restrict__ bhh1,
                float* __restrict__ hfin){
  __shared__ unsigned short xp_hi[16][60][8];
  __shared__ unsigned short xp_lo[16][60][8];
  __shared__ unsigned short h0hi[16][72], h0lo[16][72], h1hi[16][72], h1lo[16][72];

  const int tid  = threadIdx.x;
  const int lane = tid & 63;
  const int w    = tid >> 6;     // wave id: owns dims [w*16, w*16+16)
  const int c    = lane & 15;    // A-frag row (node) / D col (dim-in-tile)
  const int q    = lane >> 4;    // quad
  const int d    = w*16 + c;     // this lane's hidden dim for gate math / B rows
  const int nbase = blockIdx.x * 16;

  // stage x -> bf16 hi/lo planes  (x[n][feat][t], padded feat->8)
  for (int v = tid; v < 16*360; v += 256){
    int n = v / 360, rem = v % 360;
    int dd = rem / 60, tt = rem % 60;
    float f = x[(size_t)(nbase + n)*360 + rem];
    unsigned short hb = f2bf(f);
    xp_hi[n][tt][dd] = hb;
    xp_lo[n][tt][dd] = f2bf(f - bf2f(hb));
  }
  for (int v = tid; v < 16*60*2; v += 256){
    int n = v / 120, rem = v % 120;
    int tt = rem >> 1, dd = 6 + (rem & 1);
    xp_hi[n][tt][dd] = 0; xp_lo[n][tt][dd] = 0;
  }
  for (int v = tid; v < 16*72; v += 256){
    int n = v / 72, k = v % 72;
    h0hi[n][k] = 0; h0lo[n][k] = 0; h1hi[n][k] = 0; h1lo[n][k] = 0;
  }

  const float bi0r = bih0[d], bi0z = bih0[64+d], bi0n = bih0[128+d];
  const float bh0r = bhh0[d], bh0z = bhh0[64+d], bh0n = bhh0[128+d];
  const float bi1r = bih1[d], bi1z = bih1[64+d], bi1n = bih1[128+d];
  const float bh1r = bhh1[d], bh1z = bhh1[64+d], bh1n = bhh1[128+d];

  // weight B-fragments, resident in registers for the whole t-loop
  WF Bih0[3];
  WF Bhh0[3][2], Bih1[3][2], Bhh1[3][2];
  #pragma unroll
  for (int g = 0; g < 3; g++){
    int row = g*64 + d;
    Bih0[g] = load_wf(Wih0, 6, row, q*8, 6);
    #pragma unroll
    for (int kt = 0; kt < 2; kt++){
      Bhh0[g][kt] = load_wf(Whh0, 64, row, kt*32 + q*8, 64);
      Bih1[g][kt] = load_wf(Wih1, 64, row, kt*32 + q*8, 64);
      Bhh1[g][kt] = load_wf(Whh1, 64, row, kt*32 + q*8, 64);
    }
  }

  float h0old[4] = {0,0,0,0}, h1old[4] = {0,0,0,0};

  __syncthreads();

  #pragma unroll 1
  for (int t = 0; t < 60; t++){
    // (a) read all A-fragments that depend on pre-step state
    bf16x8 a_h0h[2], a_h0l[2], a_h1h[2], a_h1l[2];
    #pragma unroll
    for (int kt = 0; kt < 2; kt++){
      a_h0h[kt] = *(const bf16x8*)&h0hi[c][kt*32 + q*8];
      a_h0l[kt] = *(const bf16x8*)&h0lo[c][kt*32 + q*8];
      a_h1h[kt] = *(const bf16x8*)&h1hi[c][kt*32 + q*8];
      a_h1l[kt] = *(const bf16x8*)&h1lo[c][kt*32 + q*8];
    }
    bf16x8 a_xh = {}, a_xl = {};
    if (q == 0){
      a_xh = *(const bf16x8*)&xp_hi[c][t][0];
      a_xl = *(const bf16x8*)&xp_lo[c][t][0];
    }
    __syncthreads();   // (b) all reads of h0/h1 complete before any write

    // ---- layer 0 ----
    f32x4 Dr = {0,0,0,0}, Dz = {0,0,0,0}, Dni = {0,0,0,0}, Dnh = {0,0,0,0};
    Dr  = mm3(a_xh, a_xl, Bih0[0], Dr);
    Dz  = mm3(a_xh, a_xl, Bih0[1], Dz);
    Dni = mm3(a_xh, a_xl, Bih0[2], Dni);
    #pragma unroll
    for (int kt = 0; kt < 2; kt++){
      Dr  = mm3(a_h0h[kt], a_h0l[kt], Bhh0[0][kt], Dr);
      Dz  = mm3(a_h0h[kt], a_h0l[kt], Bhh0[1][kt], Dz);
      Dnh = mm3(a_h0h[kt], a_h0l[kt], Bhh0[2][kt], Dnh);
    }
    #pragma unroll
    for (int rI = 0; rI < 4; rI++){
      float rv = sigmoidf_(Dr[rI] + bi0r + bh0r);
      float zv = sigmoidf_(Dz[rI] + bi0z + bh0z);
      float nv = tanhf_(Dni[rI] + bi0n + rv*(Dnh[rI] + bh0n));
      float hnew = (1.f - zv)*nv + zv*h0old[rI];
      h0old[rI] = hnew;
      unsigned short hb = f2bf(hnew);
      int node = q*4 + rI;
      h0hi[node][d] = hb;
      h0lo[node][d] = f2bf(hnew - bf2f(hb));
    }
    __syncthreads();   // (e) h0_new (= y1_t) visible

    // ---- layer 1 ----
    bf16x8 a_yh[2], a_yl[2];
    #pragma unroll
    for (int kt = 0; kt < 2; kt++){
      a_yh[kt] = *(const bf16x8*)&h0hi[c][kt*32 + q*8];
      a_yl[kt] = *(const bf16x8*)&h0lo[c][kt*32 + q*8];
    }
    f32x4 Er = {0,0,0,0}, Ez = {0,0,0,0}, Eni = {0,0,0,0}, Enh = {0,0,0,0};
    #pragma unroll
    for (int kt = 0; kt < 2; kt++){
      Er  = mm3(a_yh[kt], a_yl[kt], Bih1[0][kt], Er);
      Ez  = mm3(a_yh[kt], a_yl[kt], Bih1[1][kt], Ez);
      Eni = mm3(a_yh[kt], a_yl[kt], Bih1[2][kt], Eni);
      Er  = mm3(a_h1h[kt], a_h1l[kt], Bhh1[0][kt], Er);
      Ez  = mm3(a_h1h[kt], a_h1l[kt], Bhh1[1][kt], Ez);
      Enh = mm3(a_h1h[kt], a_h1l[kt], Bhh1[2][kt], Enh);
    }
    #pragma unroll
    for (int rI = 0; rI < 4; rI++){
      float rv = sigmoidf_(Er[rI] + bi1r + bh1r);
      float zv = sigmoidf_(Ez[rI] + bi1z + bh1z);
      float nv = tanhf_(Eni[rI] + bi1n + rv*(Enh[rI] + bh1n));
      float hnew = (1.f - zv)*nv + zv*h1old[rI];
      h1old[rI] = hnew;
      unsigned short hb = f2bf(hnew);
      int node = q*4 + rI;
      h1hi[node][d] = hb;
      h1lo[node][d] = f2bf(hnew - bf2f(hb));
    }
    __syncthreads();   // (j) h1 writes visible before next step's reads
  }

  #pragma unroll
  for (int rI = 0; rI < 4; rI++){
    int node = nbase + q*4 + rI;
    hfin[(size_t)node*64 + d] = h1old[rI];
  }
}

// ---------------- a,c per head: a=h@W[:64], c=h@W[64:] ----------------
__global__ void ac_kernel(const float* __restrict__ hfin,
                          const float* __restrict__ W0h, const float* __restrict__ W1h,
                          const float* __restrict__ W2h, float* __restrict__ ac){
  int lane = threadIdx.x & 63;
  int node = blockIdx.x*4 + (threadIdx.x >> 6);
  float hv = hfin[(size_t)node*64 + lane];
  const float* Ws[3] = {W0h, W1h, W2h};
  #pragma unroll
  for (int h = 0; h < 3; h++){
    float pa = hv * Ws[h][lane];
    float pc = hv * Ws[h][64 + lane];
    #pragma unroll
    for (int m = 32; m >= 1; m >>= 1){
      pa += __shfl_xor(pa, m, 64);
      pc += __shfl_xor(pc, m, 64);
    }
    if (lane == 0){
      ac[(size_t)(2*h)*4000 + node]   = pa;
      ac[(size_t)(2*h+1)*4000 + node] = pc;
    }
  }
}

// ---------------- fused 3-head masked softmax + aggregation + fc ----------------
__global__ __launch_bounds__(256, 1)
void attn_kernel(const float* __restrict__ rel, const float* __restrict__ hfin,
                 const float* __restrict__ ac,
                 const float* __restrict__ b0p, const float* __restrict__ b1p,
                 const float* __restrict__ b2p,
                 const float* __restrict__ fcw, const float* __restrict__ fcb,
                 float* __restrict__ pred){
  __shared__ float wbuf[4096][4];     // mask, then combined weight, per row
  __shared__ float htile[128][68];
  __shared__ float red[3][257];
  __shared__ float aggred[4][4][64];

  const int tid = threadIdx.x;
  const int i0 = blockIdx.x*4;
  const float b[3] = {b0p[0], b1p[0], b2p[0]};

  for (int r = 0; r < 4; r++){
    const int i = i0 + r;
    float ai[3] = {ac[i], ac[2*4000 + i], ac[4*4000 + i]};
    // P1: mask -> LDS, per-head max
    float mx[3] = {-1e30f, -1e30f, -1e30f};
    for (int j = tid; j < 4096; j += 256){
      if (j < 4000){
        const float* rp = rel + ((size_t)i*4000 + j)*8;
        float4 p0 = *(const float4*)rp;
        float4 p1 = *(const float4*)(rp + 4);
        float mask = p0.x+p0.y+p0.z+p0.w + p1.x+p1.y+p1.z+p1.w;
        wbuf[j][r] = mask;
        #pragma unroll
        for (int h = 0; h < 3; h++){
          float cv = ac[(size_t)(2*h+1)*4000 + j];
          float s = ai[h] + cv + b[h];
          float wv = s > 0.f ? s : 0.01f*s;
          float val = (mask == 0.f) ? -1e6f : mask*wv;
          mx[h] = fmaxf(mx[h], val);
        }
      } else wbuf[j][r] = 0.f;
    }
    red[0][tid] = mx[0]; red[1][tid] = mx[1]; red[2][tid] = mx[2];
    __syncthreads();
    for (int s = 128; s > 0; s >>= 1){
      if (tid < s){
        red[0][tid] = fmaxf(red[0][tid], red[0][tid+s]);
        red[1][tid] = fmaxf(red[1][tid], red[1][tid+s]);
        red[2][tid] = fmaxf(red[2][tid], red[2][tid+s]);
      }
      __syncthreads();
    }
    float M[3] = {red[0][0], red[1][0], red[2][0]};
    __syncthreads();
    // P2: Z per head
    float sm[3] = {0.f, 0.f, 0.f};
    for (int j = tid; j < 4000; j += 256){
      float mask = wbuf[j][r];
      #pragma unroll
      for (int h = 0; h < 3; h++){
        float cv = ac[(size_t)(2*h+1)*4000 + j];
        float s = ai[h] + cv + b[h];
        float wv = s > 0.f ? s : 0.01f*s;
        float val = (mask == 0.f) ? -1e6f : mask*wv;
        sm[h] += __expf(val - M[h]);
      }
    }
    red[0][tid] = sm[0]; red[1][tid] = sm[1]; red[2][tid] = sm[2];
    __syncthreads();
    for (int s = 128; s > 0; s >>= 1){
      if (tid < s){
        red[0][tid] += red[0][tid+s];
        red[1][tid] += red[1][tid+s];
        red[2][tid] += red[2][tid+s];
      }
      __syncthreads();
    }
    float iZ[3] = {1.f/red[0][0], 1.f/red[1][0], 1.f/red[2][0]};
    __syncthreads();
    // P3: combined weight overwrites mask
    for (int j = tid; j < 4000; j += 256){
      float mask = wbuf[j][r];
      float wj = 0.f;
      #pragma unroll
      for (int h = 0; h < 3; h++){
        float cv = ac[(size_t)(2*h+1)*4000 + j];
        float s = ai[h] + cv + b[h];
        float wv = s > 0.f ? s : 0.01f*s;
        float val = (mask == 0.f) ? -1e6f : mask*wv;
        wj += __expf(val - M[h]) * iZ[h];
      }
      wbuf[j][r] = wj * (1.f/3.f);
    }
    __syncthreads();
  }

  // P4: agg[r][:] = sum_j w[r][j] * h[j][:]
  const int lane = tid & 63, w4 = tid >> 6;
  const int quad = lane >> 4, dg = lane & 15;
  float accv[4][4] = {{0,0,0,0},{0,0,0,0},{0,0,0,0},{0,0,0,0}};
  for (int tj = 0; tj < 4096; tj += 128){
    __syncthreads();
    for (int v = tid; v < 2048; v += 256){
      int jj = v >> 4, dd = (v & 15)*4;
      int jg = tj + jj;
      float4 hv = (jg < 4000) ? *(const float4*)&hfin[(size_t)jg*64 + dd]
                              : make_float4(0.f, 0.f, 0.f, 0.f);
      *(float4*)&htile[jj][dd] = hv;
    }
    __syncthreads();
    #pragma unroll
    for (int it = 0; it < 8; it++){
      int jl = w4*32 + it*4 + quad;
      float4 hv  = *(const float4*)&htile[jl][dg*4];
      float4 wj4 = *(const float4*)&wbuf[tj + jl][0];
      float wjr[4] = {wj4.x, wj4.y, wj4.z, wj4.w};
      float hvr[4] = {hv.x, hv.y, hv.z, hv.w};
      #pragma unroll
      for (int r2 = 0; r2 < 4; r2++)
        #pragma unroll
        for (int cc = 0; cc < 4; cc++)
          accv[r2][cc] = fmaf(wjr[r2], hvr[cc], accv[r2][cc]);
    }
  }
  #pragma unroll
  for (int r2 = 0; r2 < 4; r2++)
    #pragma unroll
    for (int cc = 0; cc < 4; cc++){
      accv[r2][cc] += __shfl_xor(accv[r2][cc], 16, 64);
      accv[r2][cc] += __shfl_xor(accv[r2][cc], 32, 64);
    }
  if (quad == 0){
    #pragma unroll
    for (int r2 = 0; r2 < 4; r2++)
      #pragma unroll
      for (int cc = 0; cc < 4; cc++)
        aggred[w4][r2][dg*4 + cc] = accv[r2][cc];
  }
  __syncthreads();
  {
    int r2 = tid >> 6, dd = tid & 63;
    float agg = aggred[0][r2][dd] + aggred[1][r2][dd] + aggred[2][r2][dd] + aggred[3][r2][dd];
    int i = i0 + r2;
    float term = hfin[(size_t)i*64 + dd]*fcw[dd] + agg*fcw[64 + dd];
    #pragma unroll
    for (int m = 32; m >= 1; m >>= 1) term += __shfl_xor(term, m, 64);
    if (dd == 0) pred[i] = term + fcb[0];
  }
}

extern "C" void kernel_launch(void* const* d_in, const int* in_sizes, int n_in,
                              void* d_out, int out_size, void* d_ws, size_t ws_size,
                              hipStream_t stream) {
  const float* x    = (const float*)d_in[0];
  const float* rel  = (const float*)d_in[1];
  const float* Wih0 = (const float*)d_in[2];
  const float* Whh0 = (const float*)d_in[3];
  const float* bih0 = (const float*)d_in[4];
  const float* bhh0 = (const float*)d_in[5];
  const float* Wih1 = (const float*)d_in[6];
  const float* Whh1 = (const float*)d_in[7];
  const float* bih1 = (const float*)d_in[8];
  const float* bhh1 = (const float*)d_in[9];
  const float* W0   = (const float*)d_in[10];
  const float* b0   = (const float*)d_in[11];
  const float* W1   = (const float*)d_in[12];
  const float* b1   = (const float*)d_in[13];
  const float* W2   = (const float*)d_in[14];
  const float* b2   = (const float*)d_in[15];
  const float* fcw  = (const float*)d_in[16];
  const float* fcb  = (const float*)d_in[17];
  float* pred = (float*)d_out;
  float* hfin = (float*)d_ws;          // 4000*64 f32
  float* ac   = hfin + 4000*64;        // 6*4000 f32

  gru_kernel<<<dim3(250), dim3(256), 0, stream>>>(x, Wih0, Whh0, bih0, bhh0,
                                                  Wih1, Whh1, bih1, bhh1, hfin);
  ac_kernel<<<dim3(1000), dim3(256), 0, stream>>>(hfin, W0, W1, W2, ac);
  attn_kernel<<<dim3(1000), dim3(256), 0, stream>>>(rel, hfin, ac, b0, b1, b2,
                                                    fcw, fcb, pred);
}

// Round 2
// 906.964 us; speedup vs baseline: 1.4567x; 1.4567x over previous
//
#include <hip/hip_runtime.h>

typedef __attribute__((ext_vector_type(8))) short bf16x8;
typedef __attribute__((ext_vector_type(4))) float f32x4;
typedef __attribute__((ext_vector_type(4))) float f4v;

__device__ __forceinline__ unsigned short f2bf(float f){
  unsigned u = __builtin_bit_cast(unsigned, f);
  u += 0x7FFFu + ((u >> 16) & 1u);
  return (unsigned short)(u >> 16);
}
__device__ __forceinline__ float bf2f(unsigned short b){
  unsigned u = ((unsigned)b) << 16;
  return __builtin_bit_cast(float, u);
}
__device__ __forceinline__ float sigmoidf_(float x){ return 1.f/(1.f + __expf(-x)); }
__device__ __forceinline__ float tanhf_(float x){
  float a = fabsf(x);
  float t = __expf(-2.f*a);
  float r = (1.f - t)/(1.f + t);
  return copysignf(r, x);
}

struct WF { bf16x8 hi, lo; };

// D += (Ah+Al)*(Bh+Bl), dropping Al*Bl  (~fp32 precision, fp32 accumulate)
__device__ __forceinline__ f32x4 mm3(bf16x8 ah, bf16x8 al, const WF& B, f32x4 D){
  D = __builtin_amdgcn_mfma_f32_16x16x32_bf16(al, B.hi, D, 0, 0, 0);
  D = __builtin_amdgcn_mfma_f32_16x16x32_bf16(ah, B.lo, D, 0, 0, 0);
  D = __builtin_amdgcn_mfma_f32_16x16x32_bf16(ah, B.hi, D, 0, 0, 0);
  return D;
}

__device__ __forceinline__ WF load_wf(const float* W, int ldk, int row, int k0, int kmax){
  WF f;
  #pragma unroll
  for (int j = 0; j < 8; j++){
    int k = k0 + j;
    float v = (k < kmax) ? W[row*ldk + k] : 0.f;
    unsigned short hb = f2bf(v);
    f.hi[j] = (short)hb;
    f.lo[j] = (short)f2bf(v - bf2f(hb));
  }
  return f;
}

// ---------------- GRU: 2 layers fused, 16 nodes per workgroup ----------------
__global__ __launch_bounds__(256, 1)
void gru_kernel(const float* __restrict__ x,
                const float* __restrict__ Wih0, const float* __restrict__ Whh0,
                const float* __restrict__ bih0, const float* __restrict__ bhh0,
                const float* __restrict__ Wih1, const float* __restrict__ Whh1,
                const float* __restrict__ bih1, const float* __restrict__ bhh1,
                float* __restrict__ hfin){
  __shared__ unsigned short xp_hi[16][60][8];
  __shared__ unsigned short xp_lo[16][60][8];
  __shared__ unsigned short h0hi[16][72], h0lo[16][72], h1hi[16][72], h1lo[16][72];

  const int tid  = threadIdx.x;
  const int lane = tid & 63;
  const int w    = tid >> 6;
  const int c    = lane & 15;
  const int q    = lane >> 4;
  const int d    = w*16 + c;
  const int nbase = blockIdx.x * 16;

  for (int v = tid; v < 16*360; v += 256){
    int n = v / 360, rem = v % 360;
    int dd = rem / 60, tt = rem % 60;
    float f = x[(size_t)(nbase + n)*360 + rem];
    unsigned short hb = f2bf(f);
    xp_hi[n][tt][dd] = hb;
    xp_lo[n][tt][dd] = f2bf(f - bf2f(hb));
  }
  for (int v = tid; v < 16*60*2; v += 256){
    int n = v / 120, rem = v % 120;
    int tt = rem >> 1, dd = 6 + (rem & 1);
    xp_hi[n][tt][dd] = 0; xp_lo[n][tt][dd] = 0;
  }
  for (int v = tid; v < 16*72; v += 256){
    int n = v / 72, k = v % 72;
    h0hi[n][k] = 0; h0lo[n][k] = 0; h1hi[n][k] = 0; h1lo[n][k] = 0;
  }

  const float bi0r = bih0[d], bi0z = bih0[64+d], bi0n = bih0[128+d];
  const float bh0r = bhh0[d], bh0z = bhh0[64+d], bh0n = bhh0[128+d];
  const float bi1r = bih1[d], bi1z = bih1[64+d], bi1n = bih1[128+d];
  const float bh1r = bhh1[d], bh1z = bhh1[64+d], bh1n = bhh1[128+d];

  WF Bih0[3];
  WF Bhh0[3][2], Bih1[3][2], Bhh1[3][2];
  #pragma unroll
  for (int g = 0; g < 3; g++){
    int row = g*64 + d;
    Bih0[g] = load_wf(Wih0, 6, row, q*8, 6);
    #pragma unroll
    for (int kt = 0; kt < 2; kt++){
      Bhh0[g][kt] = load_wf(Whh0, 64, row, kt*32 + q*8, 64);
      Bih1[g][kt] = load_wf(Wih1, 64, row, kt*32 + q*8, 64);
      Bhh1[g][kt] = load_wf(Whh1, 64, row, kt*32 + q*8, 64);
    }
  }

  float h0old[4] = {0,0,0,0}, h1old[4] = {0,0,0,0};

  __syncthreads();

  #pragma unroll 1
  for (int t = 0; t < 60; t++){
    bf16x8 a_h0h[2], a_h0l[2], a_h1h[2], a_h1l[2];
    #pragma unroll
    for (int kt = 0; kt < 2; kt++){
      a_h0h[kt] = *(const bf16x8*)&h0hi[c][kt*32 + q*8];
      a_h0l[kt] = *(const bf16x8*)&h0lo[c][kt*32 + q*8];
      a_h1h[kt] = *(const bf16x8*)&h1hi[c][kt*32 + q*8];
      a_h1l[kt] = *(const bf16x8*)&h1lo[c][kt*32 + q*8];
    }
    bf16x8 a_xh = {}, a_xl = {};
    if (q == 0){
      a_xh = *(const bf16x8*)&xp_hi[c][t][0];
      a_xl = *(const bf16x8*)&xp_lo[c][t][0];
    }
    __syncthreads();

    f32x4 Dr = {0,0,0,0}, Dz = {0,0,0,0}, Dni = {0,0,0,0}, Dnh = {0,0,0,0};
    Dr  = mm3(a_xh, a_xl, Bih0[0], Dr);
    Dz  = mm3(a_xh, a_xl, Bih0[1], Dz);
    Dni = mm3(a_xh, a_xl, Bih0[2], Dni);
    #pragma unroll
    for (int kt = 0; kt < 2; kt++){
      Dr  = mm3(a_h0h[kt], a_h0l[kt], Bhh0[0][kt], Dr);
      Dz  = mm3(a_h0h[kt], a_h0l[kt], Bhh0[1][kt], Dz);
      Dnh = mm3(a_h0h[kt], a_h0l[kt], Bhh0[2][kt], Dnh);
    }
    #pragma unroll
    for (int rI = 0; rI < 4; rI++){
      float rv = sigmoidf_(Dr[rI] + bi0r + bh0r);
      float zv = sigmoidf_(Dz[rI] + bi0z + bh0z);
      float nv = tanhf_(Dni[rI] + bi0n + rv*(Dnh[rI] + bh0n));
      float hnew = (1.f - zv)*nv + zv*h0old[rI];
      h0old[rI] = hnew;
      unsigned short hb = f2bf(hnew);
      int node = q*4 + rI;
      h0hi[node][d] = hb;
      h0lo[node][d] = f2bf(hnew - bf2f(hb));
    }
    __syncthreads();

    bf16x8 a_yh[2], a_yl[2];
    #pragma unroll
    for (int kt = 0; kt < 2; kt++){
      a_yh[kt] = *(const bf16x8*)&h0hi[c][kt*32 + q*8];
      a_yl[kt] = *(const bf16x8*)&h0lo[c][kt*32 + q*8];
    }
    f32x4 Er = {0,0,0,0}, Ez = {0,0,0,0}, Eni = {0,0,0,0}, Enh = {0,0,0,0};
    #pragma unroll
    for (int kt = 0; kt < 2; kt++){
      Er  = mm3(a_yh[kt], a_yl[kt], Bih1[0][kt], Er);
      Ez  = mm3(a_yh[kt], a_yl[kt], Bih1[1][kt], Ez);
      Eni = mm3(a_yh[kt], a_yl[kt], Bih1[2][kt], Eni);
      Er  = mm3(a_h1h[kt], a_h1l[kt], Bhh1[0][kt], Er);
      Ez  = mm3(a_h1h[kt], a_h1l[kt], Bhh1[1][kt], Ez);
      Enh = mm3(a_h1h[kt], a_h1l[kt], Bhh1[2][kt], Enh);
    }
    #pragma unroll
    for (int rI = 0; rI < 4; rI++){
      float rv = sigmoidf_(Er[rI] + bi1r + bh1r);
      float zv = sigmoidf_(Ez[rI] + bi1z + bh1z);
      float nv = tanhf_(Eni[rI] + bi1n + rv*(Enh[rI] + bh1n));
      float hnew = (1.f - zv)*nv + zv*h1old[rI];
      h1old[rI] = hnew;
      unsigned short hb = f2bf(hnew);
      int node = q*4 + rI;
      h1hi[node][d] = hb;
      h1lo[node][d] = f2bf(hnew - bf2f(hb));
    }
    __syncthreads();
  }

  #pragma unroll
  for (int rI = 0; rI < 4; rI++){
    int node = nbase + q*4 + rI;
    hfin[(size_t)node*64 + d] = h1old[rI];
  }
}

// ---------------- a,c per head: a=h@W[:64], c=h@W[64:] ----------------
__global__ void ac_kernel(const float* __restrict__ hfin,
                          const float* __restrict__ W0h, const float* __restrict__ W1h,
                          const float* __restrict__ W2h, float* __restrict__ ac){
  int lane = threadIdx.x & 63;
  int node = blockIdx.x*4 + (threadIdx.x >> 6);
  float hv = hfin[(size_t)node*64 + lane];
  const float* Ws[3] = {W0h, W1h, W2h};
  #pragma unroll
  for (int h = 0; h < 3; h++){
    float pa = hv * Ws[h][lane];
    float pc = hv * Ws[h][64 + lane];
    #pragma unroll
    for (int m = 32; m >= 1; m >>= 1){
      pa += __shfl_xor(pa, m, 64);
      pc += __shfl_xor(pc, m, 64);
    }
    if (lane == 0){
      ac[(size_t)(2*h)*4000 + node]   = pa;
      ac[(size_t)(2*h+1)*4000 + node] = pc;
    }
  }
}

// -------- fused 3-head masked softmax (no max pass) + aggregation + fc --------
// 2 rows per WG, 2000 WGs. LDS ~34 KB -> 4 blocks/CU = 16 waves/CU.
__global__ __launch_bounds__(256, 4)
void attn2_kernel(const float* __restrict__ rel, const float* __restrict__ hfin,
                  const float* __restrict__ ac,
                  const float* __restrict__ b0p, const float* __restrict__ b1p,
                  const float* __restrict__ b2p,
                  const float* __restrict__ fcw, const float* __restrict__ fcb,
                  float* __restrict__ pred){
  __shared__ float m0[4000], m1[4000];     // mask, then combined weight
  __shared__ float red[4][8];
  __shared__ float aggred[4][2][64];

  const int tid  = threadIdx.x;
  const int lane = tid & 63;
  const int w    = tid >> 6;
  const int i0   = blockIdx.x * 2;
  const float b0 = b0p[0], b1 = b1p[0], b2 = b2p[0];
  const float bh[3] = {b0, b1, b2};

  const float* c0 = ac + 1*4000;
  const float* c1 = ac + 3*4000;
  const float* c2 = ac + 5*4000;

  float ai[2][3];
  #pragma unroll
  for (int r = 0; r < 2; r++)
    #pragma unroll
    for (int h = 0; h < 3; h++)
      ai[r][h] = ac[(size_t)(2*h)*4000 + i0 + r];

  float z[2][3] = {{0.f,0.f,0.f},{0.f,0.f,0.f}};

  // Pass A: stream rel once (both rows interleaved), masks -> LDS, Z accum (no max)
  for (int j = tid; j < 4000; j += 256){
    const f4v* rp0 = (const f4v*)(rel + ((size_t)i0*4000 + j)*8);
    const f4v* rp1 = (const f4v*)(rel + ((size_t)(i0+1)*4000 + j)*8);
    f4v a0 = __builtin_nontemporal_load(rp0);
    f4v a1 = __builtin_nontemporal_load(rp0 + 1);
    f4v a2 = __builtin_nontemporal_load(rp1);
    f4v a3 = __builtin_nontemporal_load(rp1 + 1);
    float mk0 = a0[0]+a0[1]+a0[2]+a0[3] + a1[0]+a1[1]+a1[2]+a1[3];
    float mk1 = a2[0]+a2[1]+a2[2]+a2[3] + a3[0]+a3[1]+a3[2]+a3[3];
    m0[j] = mk0; m1[j] = mk1;
    float cv[3] = {c0[j], c1[j], c2[j]};
    #pragma unroll
    for (int h = 0; h < 3; h++){
      float s0 = ai[0][h] + cv[h] + bh[h];
      float s1 = ai[1][h] + cv[h] + bh[h];
      float w0 = s0 > 0.f ? s0 : 0.01f*s0;
      float w1 = s1 > 0.f ? s1 : 0.01f*s1;
      float v0 = (mk0 == 0.f) ? -1e6f : mk0*w0;
      float v1 = (mk1 == 0.f) ? -1e6f : mk1*w1;
      z[0][h] += __expf(v0);
      z[1][h] += __expf(v1);
    }
  }
  // Z reduction: wave shfl -> LDS -> combine
  #pragma unroll
  for (int r = 0; r < 2; r++)
    #pragma unroll
    for (int h = 0; h < 3; h++){
      float v = z[r][h];
      #pragma unroll
      for (int m = 32; m >= 1; m >>= 1) v += __shfl_xor(v, m, 64);
      if (lane == 0) red[w][r*3 + h] = v;
    }
  __syncthreads();
  float iZ[2][3];
  #pragma unroll
  for (int r = 0; r < 2; r++)
    #pragma unroll
    for (int h = 0; h < 3; h++)
      iZ[r][h] = 1.f/(red[0][r*3+h] + red[1][r*3+h] + red[2][r*3+h] + red[3][r*3+h]);

  // Pass B: combined normalized weight overwrites mask (own j only; no barrier needed yet)
  for (int j = tid; j < 4000; j += 256){
    float mk0 = m0[j], mk1 = m1[j];
    float cv[3] = {c0[j], c1[j], c2[j]};
    float w0s = 0.f, w1s = 0.f;
    #pragma unroll
    for (int h = 0; h < 3; h++){
      float s0 = ai[0][h] + cv[h] + bh[h];
      float s1 = ai[1][h] + cv[h] + bh[h];
      float w0 = s0 > 0.f ? s0 : 0.01f*s0;
      float w1 = s1 > 0.f ? s1 : 0.01f*s1;
      float v0 = (mk0 == 0.f) ? -1e6f : mk0*w0;
      float v1 = (mk1 == 0.f) ? -1e6f : mk1*w1;
      w0s += __expf(v0) * iZ[0][h];
      w1s += __expf(v1) * iZ[1][h];
    }
    m0[j] = w0s * (1.f/3.f);
    m1[j] = w1s * (1.f/3.f);
  }
  __syncthreads();

  // Pass C: agg[r][d] = sum_j w[r][j] * h[j][d]; wave w owns j in [w*1000, w*1000+1000)
  float acc0 = 0.f, acc1 = 0.f;
  const int jb = w * 1000;
  #pragma unroll 4
  for (int jj = 0; jj < 1000; jj++){
    int j = jb + jj;
    float hv = hfin[(size_t)j*64 + lane];
    acc0 = fmaf(m0[j], hv, acc0);
    acc1 = fmaf(m1[j], hv, acc1);
  }
  aggred[w][0][lane] = acc0;
  aggred[w][1][lane] = acc1;
  __syncthreads();
  if (tid < 128){
    int r = tid >> 6, d = tid & 63;
    float agg = aggred[0][r][d] + aggred[1][r][d] + aggred[2][r][d] + aggred[3][r][d];
    float term = hfin[(size_t)(i0+r)*64 + d]*fcw[d] + agg*fcw[64 + d];
    #pragma unroll
    for (int m = 32; m >= 1; m >>= 1) term += __shfl_xor(term, m, 64);
    if (d == 0) pred[i0 + r] = term + fcb[0];
  }
}

extern "C" void kernel_launch(void* const* d_in, const int* in_sizes, int n_in,
                              void* d_out, int out_size, void* d_ws, size_t ws_size,
                              hipStream_t stream) {
  const float* x    = (const float*)d_in[0];
  const float* rel  = (const float*)d_in[1];
  const float* Wih0 = (const float*)d_in[2];
  const float* Whh0 = (const float*)d_in[3];
  const float* bih0 = (const float*)d_in[4];
  const float* bhh0 = (const float*)d_in[5];
  const float* Wih1 = (const float*)d_in[6];
  const float* Whh1 = (const float*)d_in[7];
  const float* bih1 = (const float*)d_in[8];
  const float* bhh1 = (const float*)d_in[9];
  const float* W0   = (const float*)d_in[10];
  const float* b0   = (const float*)d_in[11];
  const float* W1   = (const float*)d_in[12];
  const float* b1   = (const float*)d_in[13];
  const float* W2   = (const float*)d_in[14];
  const float* b2   = (const float*)d_in[15];
  const float* fcw  = (const float*)d_in[16];
  const float* fcb  = (const float*)d_in[17];
  float* pred = (float*)d_out;
  float* hfin = (float*)d_ws;          // 4000*64 f32
  float* ac   = hfin + 4000*64;        // 6*4000 f32

  gru_kernel<<<dim3(250), dim3(256), 0, stream>>>(x, Wih0, Whh0, bih0, bhh0,
                                                  Wih1, Whh1, bih1, bhh1, hfin);
  ac_kernel<<<dim3(1000), dim3(256), 0, stream>>>(hfin, W0, W1, W2, ac);
  attn2_kernel<<<dim3(2000), dim3(256), 0, stream>>>(rel, hfin, ac, b0, b1, b2,
                                                     fcw, fcb, pred);
}

// Round 3
// 882.240 us; speedup vs baseline: 1.4975x; 1.0280x over previous
//
#include <hip/hip_runtime.h>

typedef __attribute__((ext_vector_type(8))) short bf16x8;
typedef __attribute__((ext_vector_type(4))) float f32x4;
typedef __attribute__((ext_vector_type(4))) float f4v;

__device__ __forceinline__ unsigned short f2bf(float f){
  unsigned u = __builtin_bit_cast(unsigned, f);
  u += 0x7FFFu + ((u >> 16) & 1u);
  return (unsigned short)(u >> 16);
}
__device__ __forceinline__ float bf2f(unsigned short b){
  unsigned u = ((unsigned)b) << 16;
  return __builtin_bit_cast(float, u);
}
__device__ __forceinline__ float sigmoidf_(float x){ return 1.f/(1.f + __expf(-x)); }
__device__ __forceinline__ float tanhf_(float x){
  float a = fabsf(x);
  float t = __expf(-2.f*a);
  float r = (1.f - t)/(1.f + t);
  return copysignf(r, x);
}

struct WF { bf16x8 hi, lo; };

// split-precision accumulate: hi-chain gets ah*Bhi, lo-chain gets al*Bhi + ah*Blo
__device__ __forceinline__ void mmsplit(bf16x8 ah, bf16x8 al, const WF& B,
                                        f32x4& Dh, f32x4& Dl){
  Dh = __builtin_amdgcn_mfma_f32_16x16x32_bf16(ah, B.hi, Dh, 0, 0, 0);
  Dl = __builtin_amdgcn_mfma_f32_16x16x32_bf16(al, B.hi, Dl, 0, 0, 0);
  Dl = __builtin_amdgcn_mfma_f32_16x16x32_bf16(ah, B.lo, Dl, 0, 0, 0);
}

__device__ __forceinline__ WF load_wf(const float* W, int ldk, int row, int k0, int kmax){
  WF f;
  #pragma unroll
  for (int j = 0; j < 8; j++){
    int k = k0 + j;
    float v = (k < kmax) ? W[row*ldk + k] : 0.f;
    unsigned short hb = f2bf(v);
    f.hi[j] = (short)hb;
    f.lo[j] = (short)f2bf(v - bf2f(hb));
  }
  return f;
}

// ---------------- GRU: 2 layers fused, 16 nodes per WG, 1 barrier/step ----------------
__global__ __launch_bounds__(256, 1)
void gru_kernel(const float* __restrict__ x,
                const float* __restrict__ Wih0, const float* __restrict__ Whh0,
                const float* __restrict__ bih0, const float* __restrict__ bhh0,
                const float* __restrict__ Wih1, const float* __restrict__ Whh1,
                const float* __restrict__ bih1, const float* __restrict__ bhh1,
                float* __restrict__ hfin){
  __shared__ unsigned short xp_hi[16][60][8];
  __shared__ unsigned short xp_lo[16][60][8];
  __shared__ unsigned short h0hi[2][16][72], h0lo[2][16][72];
  __shared__ unsigned short h1hi[2][16][72], h1lo[2][16][72];

  const int tid  = threadIdx.x;
  const int lane = tid & 63;
  const int w    = tid >> 6;
  const int c    = lane & 15;
  const int q    = lane >> 4;
  const int d    = w*16 + c;
  const int nbase = blockIdx.x * 16;

  for (int v = tid; v < 16*360; v += 256){
    int n = v / 360, rem = v % 360;
    int dd = rem / 60, tt = rem % 60;
    float f = x[(size_t)(nbase + n)*360 + rem];
    unsigned short hb = f2bf(f);
    xp_hi[n][tt][dd] = hb;
    xp_lo[n][tt][dd] = f2bf(f - bf2f(hb));
  }
  for (int v = tid; v < 16*60*2; v += 256){
    int n = v / 120, rem = v % 120;
    int tt = rem >> 1, dd = 6 + (rem & 1);
    xp_hi[n][tt][dd] = 0; xp_lo[n][tt][dd] = 0;
  }
  for (int v = tid; v < 2*16*72; v += 256){
    ((unsigned short*)h0hi)[v] = 0; ((unsigned short*)h0lo)[v] = 0;
    ((unsigned short*)h1hi)[v] = 0; ((unsigned short*)h1lo)[v] = 0;
  }

  const float bi0r = bih0[d], bi0z = bih0[64+d], bi0n = bih0[128+d];
  const float bh0r = bhh0[d], bh0z = bhh0[64+d], bh0n = bhh0[128+d];
  const float bi1r = bih1[d], bi1z = bih1[64+d], bi1n = bih1[128+d];
  const float bh1r = bhh1[d], bh1z = bhh1[64+d], bh1n = bhh1[128+d];

  WF Bih0[3];
  WF Bhh0[3][2], Bih1[3][2], Bhh1[3][2];
  #pragma unroll
  for (int g = 0; g < 3; g++){
    int row = g*64 + d;
    Bih0[g] = load_wf(Wih0, 6, row, q*8, 6);
    #pragma unroll
    for (int kt = 0; kt < 2; kt++){
      Bhh0[g][kt] = load_wf(Whh0, 64, row, kt*32 + q*8, 64);
      Bih1[g][kt] = load_wf(Wih1, 64, row, kt*32 + q*8, 64);
      Bhh1[g][kt] = load_wf(Whh1, 64, row, kt*32 + q*8, 64);
    }
  }

  float h0old[4] = {0,0,0,0}, h1old[4] = {0,0,0,0};

  __syncthreads();

  #pragma unroll 1
  for (int t = 0; t < 60; t++){
    const int p  = t & 1;
    const int qb = p ^ 1;

    // ---- layer 0: reads h0[p] (state), writes h0[qb] ----
    bf16x8 a_h0h[2], a_h0l[2];
    #pragma unroll
    for (int kt = 0; kt < 2; kt++){
      a_h0h[kt] = *(const bf16x8*)&h0hi[p][c][kt*32 + q*8];
      a_h0l[kt] = *(const bf16x8*)&h0lo[p][c][kt*32 + q*8];
    }
    bf16x8 a_xh = {}, a_xl = {};
    if (q == 0){
      a_xh = *(const bf16x8*)&xp_hi[c][t][0];
      a_xl = *(const bf16x8*)&xp_lo[c][t][0];
    }

    f32x4 RH = {0,0,0,0}, RL = {0,0,0,0};
    f32x4 ZH = {0,0,0,0}, ZL = {0,0,0,0};
    f32x4 NIH = {0,0,0,0}, NIL = {0,0,0,0};
    f32x4 NHH = {0,0,0,0}, NHL = {0,0,0,0};
    mmsplit(a_xh, a_xl, Bih0[0], RH, RL);
    mmsplit(a_xh, a_xl, Bih0[1], ZH, ZL);
    mmsplit(a_xh, a_xl, Bih0[2], NIH, NIL);
    #pragma unroll
    for (int kt = 0; kt < 2; kt++){
      mmsplit(a_h0h[kt], a_h0l[kt], Bhh0[0][kt], RH, RL);
      mmsplit(a_h0h[kt], a_h0l[kt], Bhh0[1][kt], ZH, ZL);
      mmsplit(a_h0h[kt], a_h0l[kt], Bhh0[2][kt], NHH, NHL);
    }
    #pragma unroll
    for (int rI = 0; rI < 4; rI++){
      float rv = sigmoidf_(RH[rI] + RL[rI] + bi0r + bh0r);
      float zv = sigmoidf_(ZH[rI] + ZL[rI] + bi0z + bh0z);
      float nv = tanhf_(NIH[rI] + NIL[rI] + bi0n + rv*(NHH[rI] + NHL[rI] + bh0n));
      float hnew = (1.f - zv)*nv + zv*h0old[rI];
      h0old[rI] = hnew;
      unsigned short hb = f2bf(hnew);
      int node = q*4 + rI;
      h0hi[qb][node][d] = hb;
      h0lo[qb][node][d] = f2bf(hnew - bf2f(hb));
    }
    __syncthreads();   // the ONLY barrier per step

    // ---- layer 1: reads h0[qb] (y1_t) and h1[p] (state), writes h1[qb] ----
    bf16x8 a_yh[2], a_yl[2], a_h1h[2], a_h1l[2];
    #pragma unroll
    for (int kt = 0; kt < 2; kt++){
      a_yh[kt]  = *(const bf16x8*)&h0hi[qb][c][kt*32 + q*8];
      a_yl[kt]  = *(const bf16x8*)&h0lo[qb][c][kt*32 + q*8];
      a_h1h[kt] = *(const bf16x8*)&h1hi[p][c][kt*32 + q*8];
      a_h1l[kt] = *(const bf16x8*)&h1lo[p][c][kt*32 + q*8];
    }
    f32x4 EH = {0,0,0,0}, EL = {0,0,0,0};
    f32x4 FH = {0,0,0,0}, FL = {0,0,0,0};
    f32x4 GIH = {0,0,0,0}, GIL = {0,0,0,0};
    f32x4 GHH = {0,0,0,0}, GHL = {0,0,0,0};
    #pragma unroll
    for (int kt = 0; kt < 2; kt++){
      mmsplit(a_yh[kt], a_yl[kt], Bih1[0][kt], EH, EL);
      mmsplit(a_yh[kt], a_yl[kt], Bih1[1][kt], FH, FL);
      mmsplit(a_yh[kt], a_yl[kt], Bih1[2][kt], GIH, GIL);
      mmsplit(a_h1h[kt], a_h1l[kt], Bhh1[0][kt], EH, EL);
      mmsplit(a_h1h[kt], a_h1l[kt], Bhh1[1][kt], FH, FL);
      mmsplit(a_h1h[kt], a_h1l[kt], Bhh1[2][kt], GHH, GHL);
    }
    #pragma unroll
    for (int rI = 0; rI < 4; rI++){
      float rv = sigmoidf_(EH[rI] + EL[rI] + bi1r + bh1r);
      float zv = sigmoidf_(FH[rI] + FL[rI] + bi1z + bh1z);
      float nv = tanhf_(GIH[rI] + GIL[rI] + bi1n + rv*(GHH[rI] + GHL[rI] + bh1n));
      float hnew = (1.f - zv)*nv + zv*h1old[rI];
      h1old[rI] = hnew;
      unsigned short hb = f2bf(hnew);
      int node = q*4 + rI;
      h1hi[qb][node][d] = hb;
      h1lo[qb][node][d] = f2bf(hnew - bf2f(hb));
    }
    // no end-of-step barrier: next step's pre-barrier reads touch only
    // buffers written before this step's barrier; h1[qb] is read next step
    // only after next step's barrier.
  }

  #pragma unroll
  for (int rI = 0; rI < 4; rI++){
    int node = nbase + q*4 + rI;
    hfin[(size_t)node*64 + d] = h1old[rI];
  }
}

// ---------------- a,c per head: a=h@W[:64], c=h@W[64:] ----------------
__global__ void ac_kernel(const float* __restrict__ hfin,
                          const float* __restrict__ W0h, const float* __restrict__ W1h,
                          const float* __restrict__ W2h, float* __restrict__ ac){
  int lane = threadIdx.x & 63;
  int node = blockIdx.x*4 + (threadIdx.x >> 6);
  float hv = hfin[(size_t)node*64 + lane];
  const float* Ws[3] = {W0h, W1h, W2h};
  #pragma unroll
  for (int h = 0; h < 3; h++){
    float pa = hv * Ws[h][lane];
    float pc = hv * Ws[h][64 + lane];
    #pragma unroll
    for (int m = 32; m >= 1; m >>= 1){
      pa += __shfl_xor(pa, m, 64);
      pc += __shfl_xor(pc, m, 64);
    }
    if (lane == 0){
      ac[(size_t)(2*h)*4000 + node]   = pa;
      ac[(size_t)(2*h+1)*4000 + node] = pc;
    }
  }
}

// -------- fused 3-head masked softmax (no max pass) + aggregation + fc --------
// 2 rows per WG, 2000 WGs, register-prefetched rel stream.
__global__ __launch_bounds__(256, 3)
void attn2_kernel(const float* __restrict__ rel, const float* __restrict__ hfin,
                  const float* __restrict__ ac,
                  const float* __restrict__ b0p, const float* __restrict__ b1p,
                  const float* __restrict__ b2p,
                  const float* __restrict__ fcw, const float* __restrict__ fcb,
                  float* __restrict__ pred){
  __shared__ float m0[4000], m1[4000];     // mask, then combined weight
  __shared__ float red[4][8];

  const int tid  = threadIdx.x;
  const int lane = tid & 63;
  const int w    = tid >> 6;
  const int i0   = blockIdx.x * 2;
  const float bh[3] = {b0p[0], b1p[0], b2p[0]};

  const float* c0 = ac + 1*4000;
  const float* c1 = ac + 3*4000;
  const float* c2 = ac + 5*4000;

  float ai[2][3];
  #pragma unroll
  for (int r = 0; r < 2; r++)
    #pragma unroll
    for (int h = 0; h < 3; h++)
      ai[r][h] = ac[(size_t)(2*h)*4000 + i0 + r];

  float z[2][3] = {{0.f,0.f,0.f},{0.f,0.f,0.f}};

  // Pass A: stream rel once with register prefetch; masks -> LDS; Z accum (no max)
  {
    int j = tid;
    bool have = (j < 4000);
    f4v r0, r1, r2, r3;
    if (have){
      const f4v* rp0 = (const f4v*)(rel + ((size_t)i0*4000 + j)*8);
      const f4v* rp1 = (const f4v*)(rel + ((size_t)(i0+1)*4000 + j)*8);
      r0 = __builtin_nontemporal_load(rp0);
      r1 = __builtin_nontemporal_load(rp0 + 1);
      r2 = __builtin_nontemporal_load(rp1);
      r3 = __builtin_nontemporal_load(rp1 + 1);
    }
    while (have){
      int jn = j + 256;
      bool haven = (jn < 4000);
      f4v n0, n1, n2, n3;
      if (haven){
        const f4v* rp0 = (const f4v*)(rel + ((size_t)i0*4000 + jn)*8);
        const f4v* rp1 = (const f4v*)(rel + ((size_t)(i0+1)*4000 + jn)*8);
        n0 = __builtin_nontemporal_load(rp0);
        n1 = __builtin_nontemporal_load(rp0 + 1);
        n2 = __builtin_nontemporal_load(rp1);
        n3 = __builtin_nontemporal_load(rp1 + 1);
      }
      float mk0 = r0[0]+r0[1]+r0[2]+r0[3] + r1[0]+r1[1]+r1[2]+r1[3];
      float mk1 = r2[0]+r2[1]+r2[2]+r2[3] + r3[0]+r3[1]+r3[2]+r3[3];
      m0[j] = mk0; m1[j] = mk1;
      float cv[3] = {c0[j], c1[j], c2[j]};
      #pragma unroll
      for (int h = 0; h < 3; h++){
        float s0 = ai[0][h] + cv[h] + bh[h];
        float s1 = ai[1][h] + cv[h] + bh[h];
        float w0 = s0 > 0.f ? s0 : 0.01f*s0;
        float w1 = s1 > 0.f ? s1 : 0.01f*s1;
        float v0 = (mk0 == 0.f) ? -1e6f : mk0*w0;
        float v1 = (mk1 == 0.f) ? -1e6f : mk1*w1;
        z[0][h] += __expf(v0);
        z[1][h] += __expf(v1);
      }
      r0 = n0; r1 = n1; r2 = n2; r3 = n3;
      j = jn; have = haven;
    }
  }
  #pragma unroll
  for (int r = 0; r < 2; r++)
    #pragma unroll
    for (int h = 0; h < 3; h++){
      float v = z[r][h];
      #pragma unroll
      for (int m = 32; m >= 1; m >>= 1) v += __shfl_xor(v, m, 64);
      if (lane == 0) red[w][r*3 + h] = v;
    }
  __syncthreads();
  float iZ[2][3];
  #pragma unroll
  for (int r = 0; r < 2; r++)
    #pragma unroll
    for (int h = 0; h < 3; h++)
      iZ[r][h] = 1.f/(red[0][r*3+h] + red[1][r*3+h] + red[2][r*3+h] + red[3][r*3+h]);

  // Pass B: combined normalized weight overwrites mask (own j only)
  for (int j = tid; j < 4000; j += 256){
    float mk0 = m0[j], mk1 = m1[j];
    float cv[3] = {c0[j], c1[j], c2[j]};
    float w0s = 0.f, w1s = 0.f;
    #pragma unroll
    for (int h = 0; h < 3; h++){
      float s0 = ai[0][h] + cv[h] + bh[h];
      float s1 = ai[1][h] + cv[h] + bh[h];
      float w0 = s0 > 0.f ? s0 : 0.01f*s0;
      float w1 = s1 > 0.f ? s1 : 0.01f*s1;
      float v0 = (mk0 == 0.f) ? -1e6f : mk0*w0;
      float v1 = (mk1 == 0.f) ? -1e6f : mk1*w1;
      w0s += __expf(v0) * iZ[0][h];
      w1s += __expf(v1) * iZ[1][h];
    }
    m0[j] = w0s * (1.f/3.f);
    m1[j] = w1s * (1.f/3.f);
  }
  __syncthreads();

  // Pass C: agg[r][d] = sum_j w[r][j]*h[j][d]; wave w owns j in [w*1000, (w+1)*1000)
  float acc0 = 0.f, acc1 = 0.f;
  const int jb = w * 1000;
  for (int jj = 0; jj < 1000; jj += 4){
    float4 w0 = *(const float4*)&m0[jb + jj];
    float4 w1 = *(const float4*)&m1[jb + jj];
    float w0a[4] = {w0.x, w0.y, w0.z, w0.w};
    float w1a[4] = {w1.x, w1.y, w1.z, w1.w};
    #pragma unroll
    for (int k = 0; k < 4; k++){
      float hv = hfin[(size_t)(jb + jj + k)*64 + lane];
      acc0 = fmaf(w0a[k], hv, acc0);
      acc1 = fmaf(w1a[k], hv, acc1);
    }
  }
  __syncthreads();                       // everyone done reading m0/m1
  m0[(w*2 + 0)*64 + lane] = acc0;        // reuse m0 as the cross-wave reduce buffer
  m0[(w*2 + 1)*64 + lane] = acc1;
  __syncthreads();
  if (tid < 128){
    int r = tid >> 6, d = tid & 63;
    float agg = m0[(0*2+r)*64 + d] + m0[(1*2+r)*64 + d]
              + m0[(2*2+r)*64 + d] + m0[(3*2+r)*64 + d];
    float term = hfin[(size_t)(i0+r)*64 + d]*fcw[d] + agg*fcw[64 + d];
    #pragma unroll
    for (int m = 32; m >= 1; m >>= 1) term += __shfl_xor(term, m, 64);
    if (d == 0) pred[i0 + r] = term + fcb[0];
  }
}

extern "C" void kernel_launch(void* const* d_in, const int* in_sizes, int n_in,
                              void* d_out, int out_size, void* d_ws, size_t ws_size,
                              hipStream_t stream) {
  const float* x    = (const float*)d_in[0];
  const float* rel  = (const float*)d_in[1];
  const float* Wih0 = (const float*)d_in[2];
  const float* Whh0 = (const float*)d_in[3];
  const float* bih0 = (const float*)d_in[4];
  const float* bhh0 = (const float*)d_in[5];
  const float* Wih1 = (const float*)d_in[6];
  const float* Whh1 = (const float*)d_in[7];
  const float* bih1 = (const float*)d_in[8];
  const float* bhh1 = (const float*)d_in[9];
  const float* W0   = (const float*)d_in[10];
  const float* b0   = (const float*)d_in[11];
  const float* W1   = (const float*)d_in[12];
  const float* b1   = (const float*)d_in[13];
  const float* W2   = (const float*)d_in[14];
  const float* b2   = (const float*)d_in[15];
  const float* fcw  = (const float*)d_in[16];
  const float* fcb  = (const float*)d_in[17];
  float* pred = (float*)d_out;
  float* hfin = (float*)d_ws;          // 4000*64 f32
  float* ac   = hfin + 4000*64;        // 6*4000 f32

  gru_kernel<<<dim3(250), dim3(256), 0, stream>>>(x, Wih0, Whh0, bih0, bhh0,
                                                  Wih1, Whh1, bih1, bhh1, hfin);
  ac_kernel<<<dim3(1000), dim3(256), 0, stream>>>(hfin, W0, W1, W2, ac);
  attn2_kernel<<<dim3(2000), dim3(256), 0, stream>>>(rel, hfin, ac, b0, b1, b2,
                                                     fcw, fcb, pred);
}